// Round 7
// baseline (179.976 us; speedup 1.0000x reference)
//
#include <hip/hip_runtime.h>
#include <math.h>

// Problem constants (from setup_inputs): B=16, T=8192, N=32, depth=31, 5 ops.
constexpr int N_STACK = 32;
constexpr int DEPTH = 31;
constexpr int NOPS = 5;
constexpr int BLOCK = 256;
constexpr int CH = 8;                      // steps per chunk
constexpr int NCH = 4;                     // chunks: 8,8,8,7 steps
constexpr int CHW = CH * NOPS;             // 40 dwords per full chunk row
constexpr int WBUF = 64 * CHW;             // 2560 dwords LDS per wave (10,240 B)

#define LOG_LIMF 10.0f

// Force x to be materialized in a VGPR here; the result is opaque, so the
// compiler cannot re-sink / rematerialize the producing load at the use site.
#define PIN(x) asm volatile("" : "+v"(x))

typedef float f4v __attribute__((ext_vector_type(4)));
typedef unsigned int u32;

// Direct global->LDS DMA (no VGPR round trip -> nothing to spill, the failure
// mode that invalidated R4/R5/R6). Width 4: any 4B-aligned global address.
// LDS dest is wave-uniform base; lane L lands at dest + 4*L (linear).
__device__ __forceinline__ void gll4(const float* g, float* l) {
    __builtin_amdgcn_global_load_lds(
        (const __attribute__((address_space(1))) u32*)g,
        (__attribute__((address_space(3))) u32*)l, 4, 0, 0);
}

// ---- wave-coalesced op-chunk movement -----------------------------------
// A wave's 64 op rows are contiguous: 64 x 155 dwords. Chunk c = columns
// [40c,40c+40) of each row. Flat chunk dword d = 40*r + w; call q covers
// d = 64q + lane (64 CONSECUTIVE global dwords -> ~5 line-lookups instead of
// 64). Global dword = 155r + 40c + w = d + 115r + 40c. LDS image = flat
// order: row r at dword 40r (160B pitch, 16B-aligned -> b128 row reads).
__device__ __forceinline__ void issue_full(const float* __restrict__ wop,
                                           float* wl, int lane, int c) {
#pragma unroll
    for (int q = 0; q < CHW; ++q) {
        int d = 64 * q + lane;
        int r = d / CHW;                       // magic-mul by compiler
        gll4(wop + d + 115 * r + CHW * c, wl + 64 * q);
    }
}
// Last chunk: words 120..154 (35/row); rows at 35-dword pitch in LDS.
__device__ __forceinline__ void issue_last(const float* __restrict__ wop,
                                           float* wl, int lane) {
#pragma unroll
    for (int q = 0; q < 35; ++q) {
        int d = 64 * q + lane;
        int r = d / 35;
        gll4(wop + d + 120 * r + 120, wl + 64 * q);
    }
}
// Row refill into registers at chunk boundaries (NOT on the step critical
// path). Full chunks: 10 x ds_read_b128 (row base 160*lane, 16B-aligned).
__device__ __forceinline__ void read_full(const float* wl, int lane, float* cur) {
    const f4v* rp = reinterpret_cast<const f4v*>(wl + CHW * lane);
#pragma unroll
    for (int q = 0; q < 10; ++q) {
        f4v t = rp[q];
        cur[4*q+0] = t[0]; cur[4*q+1] = t[1];
        cur[4*q+2] = t[2]; cur[4*q+3] = t[3];
    }
}
// Last chunk: 35 x ds_read_b32; bank = (35L+w)%32 = (3L+w)%32 -> exactly
// 2 lanes/bank (free, m136).
__device__ __forceinline__ void read_last(const float* wl, int lane, float* cur) {
#pragma unroll
    for (int w = 0; w < 35; ++w) cur[w] = wl[35 * lane + w];
#pragma unroll
    for (int w = 35; w < CHW; ++w) cur[w] = 0.0f;
}

// _clip_log(l) = tanh(l/10)*10, via tanh(x) = (e^{2x}-1)/(e^{2x}+1)
__device__ __forceinline__ float clip_log(float l) {
    float tx = 0.2f * l;                       // 2*(l/10)
    tx = fminf(fmaxf(tx, -80.0f), 80.0f);      // keep exp finite
    float t = __expf(tx);
    return 10.0f * (t - 1.0f) * __builtin_amdgcn_rcpf(t + 1.0f);
}

// add_log_space branch combine. Shared numeric pieces (l_same_c, nlog, zres, bx)
// are computed once outside (they do not depend on signs). sy is +acc for add,
// -acc for sub.
__device__ __forceinline__ void add_ls(float sx, float lx, float sy, float ly,
                                       float l_same_c, float nlog, bool zres, bool bx,
                                       float &s_o, float &l_o)
{
    bool zx = (sx == 0.0f);
    bool zy = (sy == 0.0f);
    bool both = (!zx) && (!zy);
    bool same_sign = (sx * sy > 0.0f);
    bool same_br = both && same_sign;
    bool opp_br  = both && !same_sign;

    float s = 0.0f, l = 0.0f;          // default: both zero
    if ((!zx) && zy) { s = sx; l = lx; }
    if (zx && (!zy)) { s = sy; l = ly; }
    if (same_br) { s = (sx > 0.0f) ? 1.0f : -1.0f; l = l_same_c; }
    if (opp_br)  { s = zres ? 0.0f : (bx ? sx : sy); l = nlog; }
    s_o = s;
    l_o = clip_log(l);                 // reference clips l_out on return
}

// Grid hard-caps occupancy at 2 waves/SIMD (131072 thr = 2048 waves on 1024
// SIMDs). Compute body / PIN schedule / unroll identical to the proven R0
// kernel. ONE structural change: op chunks move global->LDS via
// global_load_lds (wave-coalesced, ZERO staging registers), and cur[40] is
// refilled from the wave-private LDS slice once per chunk boundary.
// Per-wave divergent line-lookups for ops: 9920 -> ~780.
__global__ __launch_bounds__(BLOCK)
__attribute__((amdgpu_waves_per_eu(2, 2)))
void stack_fold_kernel(const float* __restrict__ sgn,
                       const float* __restrict__ logm,
                       const float* __restrict__ ops,
                       float* __restrict__ out, int n)
{
    __shared__ float lbuf[4 * WBUF];           // 40,960 B

    const int tid = threadIdx.x;
    const int id  = blockIdx.x * BLOCK + tid;
    if (id >= n) return;
    const int lane = tid & 63;
    float* wl = lbuf + (tid >> 6) * WBUF;

    // Per-thread contiguous slices; id*128 bytes => float4 aligned.
    const float4* sg4 = reinterpret_cast<const float4*>(sgn  + (size_t)id * N_STACK);
    const float4* lg4 = reinterpret_cast<const float4*>(logm + (size_t)id * N_STACK);
    // Wave's op region: 64 contiguous rows of 155 floats (wave-uniform base).
    const float* wop = ops + (size_t)(blockIdx.x * BLOCK + (tid & ~63)) * (DEPTH * NOPS);

    // ---- 1) stack loads (issued FIRST so PINs below wait only on these) ----
    float s_arr[N_STACK], l_arr[N_STACK];
#pragma unroll
    for (int i = 0; i < N_STACK / 4; ++i) {
        float4 a = sg4[i];
        float4 b = lg4[i];
        s_arr[4*i+0] = a.x; s_arr[4*i+1] = a.y; s_arr[4*i+2] = a.z; s_arr[4*i+3] = a.w;
        l_arr[4*i+0] = b.x; l_arr[4*i+1] = b.y; l_arr[4*i+2] = b.z; l_arr[4*i+3] = b.w;
    }

    // ---- 2) issue chunk-0 DMA (completes under S-computation) ----
    issue_full(wop, wl, lane, 0);

    // ---- 3) pin stacks (waits vmcnt down to the 40 outstanding DMAs only) ----
#pragma unroll
    for (int i = 0; i < N_STACK; ++i) { PIN(s_arr[i]); PIN(l_arr[i]); }

    // Suffix sum-of-squares of ORIGINAL logs, positions 0..30 (top excluded).
    float S = 0.0f;
#pragma unroll
    for (int i = 0; i < N_STACK - 1; ++i) S = fmaf(l_arr[i], l_arr[i], S);

    // Accumulator = top of stack.
    float as_ = s_arr[N_STACK - 1];
    float al  = l_arr[N_STACK - 1];

    // ---- 4) boundary 0: chunk-0 LDS -> cur; issue chunk-1 DMA ----
    asm volatile("s_waitcnt vmcnt(0)" ::: "memory");   // chunk-0 resident
    __builtin_amdgcn_sched_barrier(0);
    float cur[CHW];
    read_full(wl, lane, cur);
#pragma unroll
    for (int i = 0; i < CHW; ++i) PIN(cur[i]);         // lgkmcnt drains here
    __builtin_amdgcn_sched_barrier(0);                 // reads before re-fill
    issue_full(wop, wl, lane, 1);

#pragma unroll
    for (int c = 0; c < NCH; ++c) {
#pragma unroll
        for (int j = 0; j < CH; ++j) {
            const int k = c * CH + j;
            if (k < DEPTH) {
                float ss = s_arr[N_STACK - 2 - k];   // sec (original input)
                float sl = l_arr[N_STACK - 2 - k];

                float p0 = cur[NOPS*j + 0];
                float p1 = cur[NOPS*j + 1];
                float p2 = cur[NOPS*j + 2];
                float p3 = cur[NOPS*j + 3];
                float p4 = cur[NOPS*j + 4];

                // ---- shared add/sub numeric core (sign-independent) ----
                float d = sl - al;
                float mx = fmaxf(sl, al);
                float lse = mx + __logf(1.0f + __expf(-fabsf(d)));   // logaddexp
                float l_same_c = clip_log(lse);

                bool bx = (sl >= al);                 // bigger_is_x
                float big    = bx ? sl : al;
                float small_ = bx ? al : sl;
                float delta = fminf(fmaxf(small_ - big, -LOG_LIMF), -0.001f);
                float diff = __logf(1.0f - __expf(delta));           // log1p(-exp(delta))
                bool zres = (small_ == big);
                float nlog = zres ? 0.0f : (big + diff);

                // ---- add / sub branch combines ----
                float s_add, l_add, s_sub, l_sub;
                add_ls(ss, sl,  as_, al, l_same_c, nlog, zres, bx, s_add, l_add);
                add_ls(ss, sl, -as_, al, l_same_c, nlog, zres, bx, s_sub, l_sub);

                // ---- mul / div ----
                float sm   = ss * as_;
                float lmul = clip_log(sl + al);
                float ldiv = clip_log(sl - al);

                // ---- soft mix over [add, sub, mul, div, identity(sec)] ----
                float rs = p0 * s_add + p1 * s_sub + (p2 + p3) * sm + p4 * ss;
                float rl = p0 * l_add + p1 * l_sub + p2 * lmul + p3 * ldiv + p4 * sl;

                // ---- RMS rescale: slice = original logs 0..30-k ++ rl (cs = 32-k)
                const float inv_cs = 1.0f / (float)(N_STACK - k);    // compile-time
                float ms = fmaf(rl, rl, S) * inv_cs + 1e-6f;
                float scale = fminf(10.0f * __builtin_amdgcn_rsqf(ms), 1.0f);
                rl = rl * scale;

                // retire original element 30-k from the suffix sum
                S = fmaf(-sl, sl, S);

                as_ = rs;
                al  = rl;
            }
        }

        // ---- chunk boundary: chunk c+1 has been in flight for a full chunk
        //      of ALU (~2500 cyc). Wave-private LDS slice, single-buffered:
        //      reads of chunk c+1 complete (lgkmcnt via PINs) BEFORE chunk
        //      c+2's DMA is issued (sched_barrier enforces order). ----
        if (c < NCH - 1) {
            asm volatile("s_waitcnt vmcnt(0)" ::: "memory");
            __builtin_amdgcn_sched_barrier(0);
            if (c + 1 < NCH - 1) read_full(wl, lane, cur);
            else                 read_last(wl, lane, cur);
#pragma unroll
            for (int i = 0; i < CHW; ++i) PIN(cur[i]);
            __builtin_amdgcn_sched_barrier(0);
            if (c + 2 < NCH - 1)       issue_full(wop, wl, lane, c + 2);
            else if (c + 2 == NCH - 1) issue_last(wop, wl, lane);
        }
    }

    // Output: (2, B, T) flattened — [0..n) = sign, [n..2n) = log
    out[id]     = as_;
    out[n + id] = al;
}

extern "C" void kernel_launch(void* const* d_in, const int* in_sizes, int n_in,
                              void* d_out, int out_size, void* d_ws, size_t ws_size,
                              hipStream_t stream) {
    const float* sgn  = (const float*)d_in[0];
    const float* logm = (const float*)d_in[1];
    const float* ops  = (const float*)d_in[2];
    float* out = (float*)d_out;

    int n = in_sizes[0] / N_STACK;   // B*T = 131072
    int blocks = (n + BLOCK - 1) / BLOCK;
    stack_fold_kernel<<<blocks, BLOCK, 0, stream>>>(sgn, logm, ops, out, n);
}